// Round 6
// baseline (311.657 us; speedup 1.0000x reference)
//
#include <hip/hip_runtime.h>
#include <math.h>

#define SB 64
#define SS 512
#define SH 768
#define NT 36
#define TSTART 34
#define TSTOP 35
#define NC 16
#define CL 32
#define APAD 40

#define CFENCE() asm volatile("" ::: "memory")

__device__ __forceinline__ float wave_max_f(float v) {
#pragma unroll
    for (int off = 32; off > 0; off >>= 1) v = fmaxf(v, __shfl_xor(v, off, 64));
    return v;
}
__device__ __forceinline__ float wave_sum_f(float v) {
#pragma unroll
    for (int off = 32; off > 0; off >>= 1) v += __shfl_xor(v, off, 64);
    return v;
}
__device__ __forceinline__ float bcast0(float v) {
    return __uint_as_float(__builtin_amdgcn_readfirstlane(__float_as_uint(v)));
}

// ---------------- emissions: logits = leaky_relu(gather(x) @ W + b) ----------------
// 512 blocks x 256 thr. lane = row, wave q = K-quarter. 36 accs/thread in VGPRs
// (launch_bounds(256,4) -> 128-VGPR budget, no spill). Output goes through LDS
// so global stores are fully coalesced.
extern "C" __global__ __launch_bounds__(256, 4) void k_emit(
    const float* __restrict__ x1, const int* __restrict__ hidx,
    const float* __restrict__ W, const float* __restrict__ bias,
    float* __restrict__ emit)
{
    __shared__ float red[4][64][NT + 1];   // +1 pad: break stride-36 bank pattern

    int tid  = threadIdx.x;
    int lane = tid & 63;
    int q    = __builtin_amdgcn_readfirstlane(tid >> 6);
    int gr   = blockIdx.x * 64 + lane;
    int b    = gr >> 9;
    const float4* xr = (const float4*)(x1 + (size_t)(b * SS + hidx[gr]) * SH) + q * 48;
    const float*  Wq = W + (size_t)q * 192 * NT;

    float acc[NT];
#pragma unroll
    for (int j = 0; j < NT; ++j) acc[j] = 0.f;

    float4 xv = xr[0];
    for (int k4 = 0; k4 < 48; ++k4) {
        float4 xn = (k4 < 47) ? xr[k4 + 1] : xv;
        const float* wr = Wq + (size_t)(k4 * 4) * NT;   // wave-uniform -> s_load
#pragma unroll
        for (int j = 0; j < NT; ++j) acc[j] += xv.x * wr[j];
#pragma unroll
        for (int j = 0; j < NT; ++j) acc[j] += xv.y * wr[NT + j];
#pragma unroll
        for (int j = 0; j < NT; ++j) acc[j] += xv.z * wr[2 * NT + j];
#pragma unroll
        for (int j = 0; j < NT; ++j) acc[j] += xv.w * wr[3 * NT + j];
        xv = xn;
    }

#pragma unroll
    for (int j = 0; j < NT; ++j) red[q][lane][j] = acc[j];
    __syncthreads();

    // coalesced epilogue: 2304 consecutive floats per block
    float* ob = emit + (size_t)blockIdx.x * 64 * NT;
#pragma unroll
    for (int k = 0; k < 9; ++k) {
        int i = tid + k * 256;
        int r = i / NT, cx = i - r * NT;
        float v = red[0][r][cx] + red[1][r][cx] + red[2][r][cx] + red[3][r][cx]
                + bias[cx];
        ob[i] = v > 0.f ? v : 0.01f * v;
    }
}

// ---------------- fused CRF megakernel ----------------
// 128 blocks (kind 0 = forward NLL, kind 1 = viterbi; b = blockIdx & 63),
// 1024 threads = 16 waves, wave c = chunk c. Emissions staged to LDS once.
// pass0 (guess seeds) -> sync -> pass1 (seeded from LDS boundary profiles,
// scalar delta relay) -> sync -> finalize (gold score / backtrack) in-block.
extern "C" __global__ __launch_bounds__(1024, 4) void k_crf2(
    const float* __restrict__ emit, const int* __restrict__ hidx,
    const int* __restrict__ tags, const float* __restrict__ trans,
    float* __restrict__ lossp, float* __restrict__ path_out,
    float* __restrict__ score_out, unsigned char* __restrict__ bp)
{
    __shared__ float  els[SS * NT];        // 73,728 B (aliased by bpl in finalize)
    __shared__ float  trl[NT * NT];        // 5,184 B
    __shared__ float  Apro[NC][APAD];      // 2,560 B  pass-0 boundary profiles
    __shared__ float4 bc4[16][16];         // 4,096 B  per-wave broadcast buffers
    __shared__ float  dls[NC];             // 64 B     per-chunk scalar deltas
    __shared__ float  sc_val[1];
    __shared__ int    sc_tag[1];
    __shared__ int    pathl[SS];           // 2,048 B

    int tid  = threadIdx.x;
    int lane = tid & 63;
    int w    = __builtin_amdgcn_readfirstlane(tid >> 6);   // wave = chunk
    int kind = blockIdx.x >> 6;
    int b    = blockIdx.x & 63;
    const float* eb = emit + (size_t)b * SS * NT;

    // stage all 512x36 emissions: 72 slots of 1KB async DMA, split across waves
    for (int s = w; s < 72; s += 16) {
        __builtin_amdgcn_global_load_lds(
            (const __attribute__((address_space(1))) void*)(eb + s * 256 + lane * 4),
            (__attribute__((address_space(3))) void*)&els[s * 256], 16, 0, 0);
    }
    for (int i = tid; i < NT * NT; i += 1024) trl[i] = trans[i];

    // xlen (per-wave redundant)
    int xm = 0;
    const int* hb = hidx + b * SS;
#pragma unroll
    for (int k = 0; k < SS / 64; ++k) xm = max(xm, hb[lane + 64 * k]);
#pragma unroll
    for (int off = 32; off > 0; off >>= 1) xm = max(xm, __shfl_xor(xm, off, 64));
    int xlen = xm;
    int cl   = (xlen >= 1) ? ((xlen - 1) >> 5) : 0;

    __syncthreads();   // els + trl staged

    int  jj  = lane < NT ? lane : NT - 1;
    bool act = lane < NT;
    int  c   = w;
    int tb = c * CL; if (tb < 1) tb = 1;
    int te = (c + 1) * CL; if (te > xlen) te = xlen; te -= 1;   // inclusive
    float* bc = (float*)bc4[w];

    float tcol[NT];   // kind0: exp(T[i][jj]) ; kind1: T[i][jj]
#pragma unroll
    for (int i = 0; i < NT; ++i) {
        float tv = trl[i * NT + jj];
        tcol[i] = kind ? tv : __expf(tv);
    }

    // one scan pass over [tb,te]; kind selects semiring; dobp gates bp writes
    auto scan = [&](float alpha, bool dobp) -> float {
        if (kind == 0) {
            for (int t = tb; t <= te; ++t) {
                float e_t = els[t * NT + jj];
                float m = bcast0(alpha);
                float p = __expf(alpha - m);
                bc[lane] = p;
                CFENCE();
                __builtin_amdgcn_wave_barrier();
                float s0 = 0.f, s1 = 0.f, s2 = 0.f, s3 = 0.f;
#pragma unroll
                for (int k = 0; k < 9; ++k) {
                    float4 pv = bc4[w][k];
                    s0 += pv.x * tcol[4 * k];
                    s1 += pv.y * tcol[4 * k + 1];
                    s2 += pv.z * tcol[4 * k + 2];
                    s3 += pv.w * tcol[4 * k + 3];
                }
                CFENCE();
                float anew = m + __logf((s0 + s1) + (s2 + s3)) + e_t;
                alpha = act ? anew : -1e30f;
            }
        } else {
            for (int t = tb; t <= te; ++t) {
                float e_t = els[t * NT + jj];
                bc[lane] = alpha;
                CFENCE();
                __builtin_amdgcn_wave_barrier();
                float b0 = -1e30f, b1 = -1e30f, b2 = -1e30f, b3 = -1e30f;
                int   i0 = 0, i1 = 1, i2 = 2, i3 = 3;
#pragma unroll
                for (int k = 0; k < 9; ++k) {
                    float4 dv = bc4[w][k];
                    float c0 = dv.x + tcol[4 * k];
                    float c1 = dv.y + tcol[4 * k + 1];
                    float c2 = dv.z + tcol[4 * k + 2];
                    float c3 = dv.w + tcol[4 * k + 3];
                    if (c0 > b0) { b0 = c0; i0 = 4 * k; }
                    if (c1 > b1) { b1 = c1; i1 = 4 * k + 1; }
                    if (c2 > b2) { b2 = c2; i2 = 4 * k + 2; }
                    if (c3 > b3) { b3 = c3; i3 = 4 * k + 3; }
                }
                CFENCE();
                float best = b0; int bi = i0;
                if (b1 > best || (b1 == best && i1 < bi)) { best = b1; bi = i1; }
                if (b2 > best || (b2 == best && i2 < bi)) { best = b2; bi = i2; }
                if (b3 > best || (b3 == best && i3 < bi)) { best = b3; bi = i3; }
                float dnew = best + e_t;
                alpha = act ? dnew : -1e30f;
                if (dobp && act)
                    bp[((size_t)b * SS + t) * 64 + jj] = (unsigned char)bi;
            }
        }
        return alpha;
    };

    // seeds
    float seed0 = act ? (els[jj] + trl[TSTART * NT + jj]) : -1e30f;   // exact c==0

    // ---- pass 0: guess seed (emission at boundary) ----
    float a0;
    if (c == 0) a0 = seed0;
    else        a0 = act ? els[(c * CL - 1) * NT + jj] : -1e30f;
    a0 = scan(a0, false);
    if (act) Apro[c][jj] = a0;
    __syncthreads();

    // ---- pass 1: seed from previous chunk's pass-0 profile ----
    float a0prev = Apro[c][0];     // scalar: this chunk's pass-0 end (tag 0)
    float a1;
    if (c == 0) a1 = seed0;
    else        a1 = act ? Apro[c - 1][jj] : -1e30f;
    a1 = scan(a1, true);

    if (lane == 0) dls[c] = bcast0(a1) - a0prev;
    if (c == cl) {
        float ff = act ? (a1 + trl[jj * NT + TSTOP]) : -1e30f;
        if (kind == 0) {
            float M = wave_max_f(ff);
            float ssum = wave_sum_f(__expf(ff - M));
            if (lane == 0) sc_val[0] = M + __logf(ssum);
        } else {
            float bv = ff; int bi = lane;
#pragma unroll
            for (int off = 32; off > 0; off >>= 1) {
                float ov = __shfl_xor(bv, off, 64);
                int   oi = __shfl_xor(bi, off, 64);
                if (ov > bv || (ov == bv && oi < bi)) { bv = ov; bi = oi; }
            }
            if (lane == 0) { sc_val[0] = bv; sc_tag[0] = bi; }
        }
    }
    __syncthreads();   // dls, sc_*, bp(global, same CU) ready

    // ---- finalize ----
    if (kind == 0) {
        if (w == 0) {
            float kf = 0.f;
            for (int k = 0; k < cl; ++k) kf += dls[k];
            const int* tg = tags + b * SS;
            float g = 0.f;
            for (int t = lane; t < SS; t += 64) {
                if (t < xlen) {
                    int tt = tg[t];
                    g += els[t * NT + tt];
                    if (t >= 1) g += trl[tg[t - 1] * NT + tt];
                }
            }
            g = wave_sum_f(g);
            if (lane == 0) {
                int lt = (xlen >= 1) ? tg[xlen - 1] : tg[0];
                float gold = g + trl[TSTART * NT + tg[0]] + trl[lt * NT + TSTOP];
                lossp[b] = (sc_val[0] + kf) - gold;
            }
        }
    } else {
        // stage this batch's backpointers into LDS (alias over els: done with it)
        unsigned char* bpl = (unsigned char*)els;
        const int4* src = (const int4*)(bp + (size_t)b * SS * 64);
        int4* dst = (int4*)bpl;
        for (int i = tid; i < SS * 4; i += 1024) dst[i] = src[i];
        __syncthreads();
        if (w == 0) {
            float kv = 0.f;
            for (int k = 0; k < cl; ++k) kv += dls[k];
            int v = sc_tag[0];
            if (lane == 0) {
                score_out[b] = sc_val[0] + kv;
                if (xlen >= 1) pathl[xlen - 1] = v;
            }
            // backtrack: row loads independent; chain = shfl only (8-deep groups)
            if (xlen >= 1) {
                int t = xlen - 1;
                while (t >= 1) {
                    int n = t < 8 ? t : 8;
                    int r0 = bpl[t * 64 + lane];
                    int r1 = (n > 1) ? bpl[(t - 1) * 64 + lane] : 0;
                    int r2 = (n > 2) ? bpl[(t - 2) * 64 + lane] : 0;
                    int r3 = (n > 3) ? bpl[(t - 3) * 64 + lane] : 0;
                    int r4 = (n > 4) ? bpl[(t - 4) * 64 + lane] : 0;
                    int r5 = (n > 5) ? bpl[(t - 5) * 64 + lane] : 0;
                    int r6 = (n > 6) ? bpl[(t - 6) * 64 + lane] : 0;
                    int r7 = (n > 7) ? bpl[(t - 7) * 64 + lane] : 0;
                    v = __shfl(r0, v, 64); if (lane == 0) pathl[t - 1] = v;
                    if (n > 1) { v = __shfl(r1, v, 64); if (lane == 0) pathl[t - 2] = v; }
                    if (n > 2) { v = __shfl(r2, v, 64); if (lane == 0) pathl[t - 3] = v; }
                    if (n > 3) { v = __shfl(r3, v, 64); if (lane == 0) pathl[t - 4] = v; }
                    if (n > 4) { v = __shfl(r4, v, 64); if (lane == 0) pathl[t - 5] = v; }
                    if (n > 5) { v = __shfl(r5, v, 64); if (lane == 0) pathl[t - 6] = v; }
                    if (n > 6) { v = __shfl(r6, v, 64); if (lane == 0) pathl[t - 7] = v; }
                    if (n > 7) { v = __shfl(r7, v, 64); if (lane == 0) pathl[t - 8] = v; }
                    t -= n;
                }
            }
            CFENCE();
            __builtin_amdgcn_wave_barrier();   // pathl by lane0 -> all lanes (same wave)
            float* op = path_out + (size_t)b * SS;
            for (int t = lane; t < SS; t += 64)
                op[t] = (t < xlen) ? (float)pathl[t] : 0.0f;
        }
    }
}

// ---------------- final loss reduction ----------------
extern "C" __global__ __launch_bounds__(64) void k_loss(
    const float* __restrict__ lossp, float* __restrict__ out)
{
    float v = lossp[threadIdx.x];
    v = wave_sum_f(v);
    if (threadIdx.x == 0) out[0] = v;
}

extern "C" void kernel_launch(void* const* d_in, const int* in_sizes, int n_in,
                              void* d_out, int out_size, void* d_ws, size_t ws_size,
                              hipStream_t stream)
{
    const float* x1    = (const float*)d_in[0];
    const int*   hidx  = (const int*)d_in[1];
    const int*   tags  = (const int*)d_in[2];
    const float* W     = (const float*)d_in[3];
    const float* bias  = (const float*)d_in[4];
    const float* trans = (const float*)d_in[5];
    float* out = (float*)d_out;

    float* emit       = (float*)d_ws;                    // 64*512*36 floats
    float* lossp      = emit + (size_t)SB * SS * NT;     // 64
    unsigned char* bp = (unsigned char*)(lossp + SB);    // 64*512*64 B (16B-aligned)

    hipLaunchKernelGGL(k_emit, dim3(SB * SS / 64), dim3(256), 0, stream,
                       x1, hidx, W, bias, emit);
    hipLaunchKernelGGL(k_crf2, dim3(128), dim3(1024), 0, stream,
                       emit, hidx, tags, trans, lossp, out + 1, out + 1 + SB * SS, bp);
    hipLaunchKernelGGL(k_loss, dim3(1), dim3(64), 0, stream, lossp, out);
}